// Round 8
// baseline (215.827 us; speedup 1.0000x reference)
//
#include <hip/hip_runtime.h>

#define N_NODES 50000
#define N_EDGES 800000
#define IN_DIM  128
#define HID_DIM 128
#define OUT_DIM 64

#define NPAD 50176                          // N_NODES rounded up (multiple of 128)
#define CAP  64                             // fixed CSR slots/node (max deg ~36, Poisson(16))
#define GEMM1B ((N_NODES + 63) / 64)        // 782 gemm1 blocks (64 rows each, 256 thr)
#define FILLB (N_EDGES / 256)               // 3125 fill blocks, exact
#define INITB 24                            // 16 w1t + 8 w2t blocks (also zero cnt)

typedef __attribute__((ext_vector_type(8))) short bf16x8;   // 8 bf16 in 4 VGPRs
typedef __attribute__((ext_vector_type(4))) float f32x4;

// float -> bf16 (round-to-nearest-even), as ushort
__device__ __forceinline__ unsigned short f2bf(float f) {
    unsigned u = __float_as_uint(f);
    u += 0x7fffu + ((u >> 16) & 1u);
    return (unsigned short)(u >> 16);
}
// bf16 pair unpack from a uint (little-endian: low ushort first)
__device__ __forceinline__ float bflo(unsigned u) { return __uint_as_float(u << 16); }
__device__ __forceinline__ float bfhi(unsigned u) { return __uint_as_float(u & 0xffff0000u); }

// accumulate one uint4 (8 bf16) into acc[8]
#define ACC8(u)  do { \
    acc[0] += bflo(u.x); acc[1] += bfhi(u.x); \
    acc[2] += bflo(u.y); acc[3] += bfhi(u.y); \
    acc[4] += bflo(u.z); acc[5] += bfhi(u.z); \
    acc[6] += bflo(u.w); acc[7] += bfhi(u.w); } while (0)

// accumulate one uint4 scaled by sc_ (v_fmac). Param must NOT be named x/y/z/w.
#define FMA8(u, sc_)  do { \
    acc[0] += bflo(u.x) * (sc_); acc[1] += bfhi(u.x) * (sc_); \
    acc[2] += bflo(u.y) * (sc_); acc[3] += bfhi(u.y) * (sc_); \
    acc[4] += bflo(u.z) * (sc_); acc[5] += bfhi(u.z) * (sc_); \
    acc[6] += bflo(u.w) * (sc_); acc[7] += bfhi(u.w) * (sc_); } while (0)

// deg -> dinv (reference: deg>0 ? rsqrt(deg) : 0)
__device__ __forceinline__ float deg2dinv(int deg) {
    return (deg > 0) ? rsqrtf((float)deg) : 0.0f;
}

// ---------------- dispatch 1: init -- W^T prep + zero cnt (replaces memset) --------

__global__ __launch_bounds__(256) void init_kernel(const float* __restrict__ W1,
                                                   const float* __restrict__ W2,
                                                   unsigned short* __restrict__ w1t,
                                                   unsigned short* __restrict__ w2t,
                                                   int* __restrict__ cnt) {
    int bid = blockIdx.x;
    int tid = threadIdx.x;
    if (bid < 16) {
        // W1T[c][k] = bf16(W1[k][c]); 128x128 -> 4096 ushort4
        int idx = bid * 256 + tid;
        int c = idx >> 5, k4 = (idx & 31) * 4;
        ushort4 o;
        o.x = f2bf(W1[(k4 + 0) * 128 + c]);
        o.y = f2bf(W1[(k4 + 1) * 128 + c]);
        o.z = f2bf(W1[(k4 + 2) * 128 + c]);
        o.w = f2bf(W1[(k4 + 3) * 128 + c]);
        *(ushort4*)(w1t + c * 128 + k4) = o;
    } else {
        // W2T[c][k] = bf16(W2[k][c]); 64x128 -> 2048 ushort4
        int idx = (bid - 16) * 256 + tid;
        int c = idx >> 5, k4 = (idx & 31) * 4;
        ushort4 o;
        o.x = f2bf(W2[(k4 + 0) * 64 + c]);
        o.y = f2bf(W2[(k4 + 1) * 64 + c]);
        o.z = f2bf(W2[(k4 + 2) * 64 + c]);
        o.w = f2bf(W2[(k4 + 3) * 64 + c]);
        *(ushort4*)(w2t + c * 128 + k4) = o;
    }
    // all 24 blocks: grid-stride zero of cnt (NPAD ints = 12544 int4)
    int4 z = {0, 0, 0, 0};
    for (int i = bid * 256 + tid; i < NPAD / 4; i += INITB * 256)
        ((int4*)cnt)[i] = z;
}

// ---------------- dispatch 2: atomic CSR fill + GEMM1 (independent, fused) --------
// Fill is atomic-bound with idle pipes (r7 PMC: VALUBusy 0.46%, MfmaUtil 0, HBM 13%)
// -> GEMM1's MFMA work rides nearly free. GEMM1 writes RAW bf16(x@W1) (no dinv, no
// cnt read) so there is NO intra-dispatch dependency; dinv is applied downstream in
// agg1 via on-the-fly rsqrt(cnt[s]) (round-2 precedent: identical absmax).

__global__ __launch_bounds__(256) void fill_gemm1_kernel(const int* __restrict__ src,
                                                         const int* __restrict__ dst,
                                                         int* __restrict__ cnt,
                                                         unsigned short* __restrict__ csr_src,
                                                         const float* __restrict__ x,
                                                         const unsigned short* __restrict__ w1t,
                                                         unsigned short* __restrict__ h1b) {
    int bid = blockIdx.x;
    if (bid < FILLB) {
        // depth-1 atomic chains: 800k independent atomics (r15 measured win vs depth-4)
        int e = bid * 256 + threadIdx.x;     // exact: FILLB*256 == N_EDGES
        int s = src[e], d = dst[e];
        int slot = atomicAdd(&cnt[d], 1);
        if (slot < CAP) csr_src[(d << 6) + slot] = (unsigned short)s;
        return;
    }

    // ---- GEMM1 (MFMA, inline fp32->bf16 A-cast): h1b = bf16(x @ W1), raw ----
    int gb = bid - FILLB;
    int wave = threadIdx.x >> 6;
    int lane = threadIdx.x & 63;
    int n = lane & 15, quad = lane >> 4;
    int row0 = gb * 64 + wave * 16;

    int arow = row0 + n;
    if (arow >= N_NODES) arow = N_NODES - 1;             // clamp (stores guarded)
    const float* aptr = x + (size_t)arow * 128 + quad * 8;
    const unsigned short* bbase = w1t + (size_t)n * 128 + quad * 8;

    f32x4 acc[8];
#pragma unroll
    for (int t = 0; t < 8; ++t) acc[t] = (f32x4){0.f, 0.f, 0.f, 0.f};

#pragma unroll
    for (int w4 = 0; w4 < 4; ++w4) {
        float4 f0 = *(const float4*)(aptr + w4 * 32);
        float4 f1 = *(const float4*)(aptr + w4 * 32 + 4);
        bf16x8 af;
        af[0] = (short)f2bf(f0.x); af[1] = (short)f2bf(f0.y);
        af[2] = (short)f2bf(f0.z); af[3] = (short)f2bf(f0.w);
        af[4] = (short)f2bf(f1.x); af[5] = (short)f2bf(f1.y);
        af[6] = (short)f2bf(f1.z); af[7] = (short)f2bf(f1.w);
#pragma unroll
        for (int t = 0; t < 8; ++t) {
            bf16x8 bf = *(const bf16x8*)(bbase + (size_t)t * 2048 + w4 * 32);
            acc[t] = __builtin_amdgcn_mfma_f32_16x16x32_bf16(af, bf, acc[t], 0, 0, 0);
        }
    }

#pragma unroll
    for (int r = 0; r < 4; ++r) {
        int row = row0 + quad * 4 + r;
        if (row < N_NODES) {
            unsigned short* o = h1b + (size_t)row * 128 + n;
#pragma unroll
            for (int t = 0; t < 8; ++t) o[t * 16] = f2bf(acc[t][r]);
        }
    }
}

// ---------------- dispatch 3: fused agg1 + GEMM2 ----------------
// h1b is raw x@W1; dinv[s] applied per-edge via FMA8 with on-the-fly rsqrt(cnt[s])
// (cnt is 200KB, L2-resident; 16 lanes/node share the broadcast load). dn for the
// node comes free from the already-loaded m = cnt[node].

#define A1T_STRIDE 136

__global__ __launch_bounds__(256) void agg1_gemm2_fused(const unsigned short* __restrict__ csr_src,
                                                        const int* __restrict__ cnt,
                                                        const float* __restrict__ b1,
                                                        const unsigned short* __restrict__ h1b,
                                                        const unsigned short* __restrict__ w2t,
                                                        unsigned short* __restrict__ h2b) {
    __shared__ unsigned short a1t[16 * A1T_STRIDE];      // 16 x 128 bf16, padded

    int node0 = blockIdx.x * 16;
    int g = threadIdx.x >> 4;        // node within block
    int q = threadIdx.x & 15;        // uint4 slot (channels 8q..8q+7)
    int node = node0 + g;            // always < N_NODES (50000 = 3125*16)
    int start = node << 6;           // fixed-stride CSR row
    int m = cnt[node];
    float dn = deg2dinv(m);
    if (m > CAP) m = CAP;            // never taken; bounds safety

    float acc[8] = {};
    int j = 0;
    for (; j + 7 < m; j += 8) {
        ushort4 sa = *(const ushort4*)(csr_src + start + j);
        ushort4 sb = *(const ushort4*)(csr_src + start + j + 4);
        float d0 = deg2dinv(cnt[sa.x]);
        float d1 = deg2dinv(cnt[sa.y]);
        float d2 = deg2dinv(cnt[sa.z]);
        float d3 = deg2dinv(cnt[sa.w]);
        float d4 = deg2dinv(cnt[sb.x]);
        float d5 = deg2dinv(cnt[sb.y]);
        float d6 = deg2dinv(cnt[sb.z]);
        float d7 = deg2dinv(cnt[sb.w]);
        uint4 u0 = ((const uint4*)(h1b + (size_t)sa.x * 128))[q];
        uint4 u1 = ((const uint4*)(h1b + (size_t)sa.y * 128))[q];
        uint4 u2 = ((const uint4*)(h1b + (size_t)sa.z * 128))[q];
        uint4 u3 = ((const uint4*)(h1b + (size_t)sa.w * 128))[q];
        uint4 u4 = ((const uint4*)(h1b + (size_t)sb.x * 128))[q];
        uint4 u5 = ((const uint4*)(h1b + (size_t)sb.y * 128))[q];
        uint4 u6 = ((const uint4*)(h1b + (size_t)sb.z * 128))[q];
        uint4 u7 = ((const uint4*)(h1b + (size_t)sb.w * 128))[q];
        FMA8(u0, d0); FMA8(u1, d1); FMA8(u2, d2); FMA8(u3, d3);
        FMA8(u4, d4); FMA8(u5, d5); FMA8(u6, d6); FMA8(u7, d7);
    }
    for (; j + 3 < m; j += 4) {
        ushort4 sa = *(const ushort4*)(csr_src + start + j);
        float d0 = deg2dinv(cnt[sa.x]);
        float d1 = deg2dinv(cnt[sa.y]);
        float d2 = deg2dinv(cnt[sa.z]);
        float d3 = deg2dinv(cnt[sa.w]);
        uint4 u0 = ((const uint4*)(h1b + (size_t)sa.x * 128))[q];
        uint4 u1 = ((const uint4*)(h1b + (size_t)sa.y * 128))[q];
        uint4 u2 = ((const uint4*)(h1b + (size_t)sa.z * 128))[q];
        uint4 u3 = ((const uint4*)(h1b + (size_t)sa.w * 128))[q];
        FMA8(u0, d0); FMA8(u1, d1); FMA8(u2, d2); FMA8(u3, d3);
    }
    for (; j < m; ++j) {
        int s0 = csr_src[start + j];
        float d0 = deg2dinv(cnt[s0]);
        uint4 u0 = ((const uint4*)(h1b + (size_t)s0 * 128))[q];
        FMA8(u0, d0);
    }

    {
        float4 bA = ((const float4*)b1)[2 * q];
        float4 bB = ((const float4*)b1)[2 * q + 1];
        ushort4 oA, oB;
        oA.x = f2bf(fmaxf(acc[0] * dn + bA.x, 0.f));
        oA.y = f2bf(fmaxf(acc[1] * dn + bA.y, 0.f));
        oA.z = f2bf(fmaxf(acc[2] * dn + bA.z, 0.f));
        oA.w = f2bf(fmaxf(acc[3] * dn + bA.w, 0.f));
        oB.x = f2bf(fmaxf(acc[4] * dn + bB.x, 0.f));
        oB.y = f2bf(fmaxf(acc[5] * dn + bB.y, 0.f));
        oB.z = f2bf(fmaxf(acc[6] * dn + bB.z, 0.f));
        oB.w = f2bf(fmaxf(acc[7] * dn + bB.w, 0.f));
        ushort4* o = (ushort4*)(a1t + g * A1T_STRIDE + q * 8);
        o[0] = oA;
        o[1] = oB;
    }
    __syncthreads();

    // Phase 2: MFMA 16 rows x 16 cols per wave; h2b = bf16(dinv_row * (a1 @ W2))
    int wave = threadIdx.x >> 6;
    int lane = threadIdx.x & 63;
    int n = lane & 15, quad = lane >> 4;
    const unsigned short* bbase = w2t + (size_t)(wave * 16 + n) * 128 + quad * 8;
    const unsigned short* abase = a1t + (size_t)n * A1T_STRIDE + quad * 8;

    f32x4 c2 = (f32x4){0.f, 0.f, 0.f, 0.f};
#pragma unroll
    for (int w4 = 0; w4 < 4; ++w4) {
        bf16x8 af = *(const bf16x8*)(abase + w4 * 32);
        bf16x8 bf = *(const bf16x8*)(bbase + w4 * 32);
        c2 = __builtin_amdgcn_mfma_f32_16x16x32_bf16(af, bf, c2, 0, 0, 0);
    }

#pragma unroll
    for (int r = 0; r < 4; ++r) {
        int row = node0 + quad * 4 + r;
        float dr = deg2dinv(cnt[row]);
        h2b[(size_t)row * 64 + wave * 16 + n] = f2bf(c2[r] * dr);
    }
}

// ---------------- dispatch 4: agg2: out[n] = b2 + dinv[n] * sum h2b[src_e] ----------

__global__ __launch_bounds__(256) void agg2_kernel(const unsigned short* __restrict__ csr_src,
                                                   const int* __restrict__ cnt,
                                                   const float* __restrict__ b2,
                                                   const unsigned short* __restrict__ h2b,
                                                   float* __restrict__ out) {
    int node = blockIdx.x * 4 + (threadIdx.x >> 6);
    if (node >= N_NODES) return;
    int lane = threadIdx.x & 63;
    int grp = lane >> 3;         // 8 groups: edge j = grp + 8t
    int q   = lane & 7;          // uint4 slot (channels 8q..8q+7)
    int start = node << 6;       // fixed-stride CSR row
    int m = cnt[node];
    float dn = deg2dinv(m);
    if (m > CAP) m = CAP;

    float acc[8] = {};

    int j = grp;
    for (; j + 8 < m; j += 16) {
        int s0 = csr_src[start + j];
        int s1 = csr_src[start + j + 8];
        uint4 u0 = ((const uint4*)(h2b + (size_t)s0 * 64))[q];
        uint4 u1 = ((const uint4*)(h2b + (size_t)s1 * 64))[q];
        ACC8(u0); ACC8(u1);
    }
    if (j < m) {
        int s0 = csr_src[start + j];
        uint4 u0 = ((const uint4*)(h2b + (size_t)s0 * 64))[q];
        ACC8(u0);
    }

#pragma unroll
    for (int d = 8; d <= 32; d <<= 1) {
#pragma unroll
        for (int c = 0; c < 8; ++c) acc[c] += __shfl_xor(acc[c], d, 64);
    }

    if (lane < 8) {
        float4 bA = ((const float4*)b2)[2 * q];
        float4 bB = ((const float4*)b2)[2 * q + 1];
        float4 rA, rB;
        rA.x = acc[0] * dn + bA.x;
        rA.y = acc[1] * dn + bA.y;
        rA.z = acc[2] * dn + bA.z;
        rA.w = acc[3] * dn + bA.w;
        rB.x = acc[4] * dn + bB.x;
        rB.y = acc[5] * dn + bB.y;
        rB.z = acc[6] * dn + bB.z;
        rB.w = acc[7] * dn + bB.w;
        float4* o = (float4*)(out + (size_t)node * 64);
        o[2 * q] = rA;
        o[2 * q + 1] = rB;
    }
}

// ---------------- launch ----------------

extern "C" void kernel_launch(void* const* d_in, const int* in_sizes, int n_in,
                              void* d_out, int out_size, void* d_ws, size_t ws_size,
                              hipStream_t stream) {
    const float* x  = (const float*)d_in[0];
    const int*   ei = (const int*)d_in[1];       // [2, E]: src = ei[0..E), dst = ei[E..2E)
    const float* W1 = (const float*)d_in[2];
    const float* b1 = (const float*)d_in[3];
    const float* W2 = (const float*)d_in[4];
    const float* b2 = (const float*)d_in[5];
    float* out = (float*)d_out;

    const int* src = ei;
    const int* dst = ei + N_EDGES;

    // workspace layout (16B-aligned regions)
    char* ws = (char*)d_ws;
    int*   cnt       = (int*)ws;                                 // NPAD
    unsigned short* csr_src = (unsigned short*)(cnt + NPAD);     // N_NODES*CAP ushort (6.4MB)
    unsigned short* h1b = csr_src + (size_t)N_NODES * CAP;       // 50000*128 bf16
    unsigned short* h2b = h1b + (size_t)N_NODES * HID_DIM;       // 50000*64 bf16
    unsigned short* w1t = h2b + (size_t)N_NODES * OUT_DIM;       // 128*128 bf16
    unsigned short* w2t = w1t + 128 * 128;                       // 64*128 bf16

    // 1. W^T prep + zero cnt (replaces hipMemsetAsync)
    init_kernel<<<INITB, 256, 0, stream>>>(W1, W2, w1t, w2t, cnt);

    // 2. atomic CSR fill + GEMM1 (GEMM1 hides under the atomic-bound fill: r7 PMC
    //    showed 46us with VALU 0.46%, MFMA 0, HBM 13% -> idle host)
    fill_gemm1_kernel<<<FILLB + GEMM1B, 256, 0, stream>>>(src, dst, cnt, csr_src,
                                                          x, w1t, h1b);

    // 3. fused: a1 = relu(b1 + dinv_d * sum dinv_s*h1raw_s);  h2b = bf16(dinv*(a1@W2))
    agg1_gemm2_fused<<<N_NODES / 16, 256, 0, stream>>>(csr_src, cnt, b1, h1b, w2t, h2b);

    // 4. out = b2 + dinv * gather(h2b)
    agg2_kernel<<<(N_NODES + 3) / 4, 256, 0, stream>>>(csr_src, cnt, b2, h2b, out);
}